// Round 3
// baseline (923.749 us; speedup 1.0000x reference)
//
#include <hip/hip_runtime.h>

#define D      1024
#define SEQ    128
#define BATCH  256
#define DQ     256
#define TEXTC  768

typedef float f32x4 __attribute__((ext_vector_type(4)));

#define GEMM_WAVES   512   // 256 blocks x waves 0,1
#define WRITE_WAVES  1536  // 256 blocks x waves 2..7
#define NROWS        (BATCH * SEQ)   // 32768

// Persistent device flags (zero-init at module load; self-reset each launch,
// so graph replays see 0 again — no memset dispatch needed).
__device__ int g_done = 0;   // GEMM waves completed (target GEMM_WAVES)
__device__ int g_exit = 0;   // writer waves completed (target WRITE_WAVES)

// ---------------------------------------------------------------------------
// ONE kernel, wave-specialized, grid 256 x 512 (1 block/CU => all blocks
// co-resident by construction; spin-wait is deadlock-free).
//   waves 0-1 : full-K (K=1024) GEMM, wave-private 16x32 tile -> comb[256][1024]
//               (1 MB, stays in L2/L3). act = [relu(sv@W1+b1) ; captions],
//               W = [style_w2 ; text_w], bias added once. Then release-add
//               g_done.
//   waves 2-7 : 21-22 rows each (row = wid + 1536*r).
//               phase 1: mask + all et!=1 rows (~80% of the 134 MB output)
//                        — this is the ~14 us shadow hiding the GEMM.
//               wait   : acquire-spin g_done == 512, __threadfence (L2 inv).
//               phase 2: et==1 rows, + comb[b] (L2/L3 hit).
//               last exiting wave resets both flags.
// ---------------------------------------------------------------------------
__global__ __launch_bounds__(512, 2) void fused_all(
    const int* __restrict__ types,           // [256][128]
    const int* __restrict__ indices,         // [256][128]
    const float* __restrict__ type_emb,      // [5][1024]
    const float* __restrict__ pos_emb,       // [128][1024]
    const float* __restrict__ final_pos_emb, // [128][1024]
    const float* __restrict__ style_vectors, // [256][5]
    const float* __restrict__ page_captions, // [256][768]
    const float* __restrict__ style_w1,      // [5][256]
    const float* __restrict__ style_b1,      // [256]
    const float* __restrict__ style_w2,      // [256][1024]
    const float* __restrict__ style_b2,      // [1024]
    const float* __restrict__ text_w,        // [768][1024]
    const float* __restrict__ text_b,        // [1024]
    float* __restrict__ comb,                // [256][1024] (workspace)
    float* __restrict__ out_emb,             // [256][128][1024]
    float* __restrict__ out_mask)            // [256][128]
{
    __shared__ float As[2][32][17];   // [gemm-wave][k][m], pad 17
    __shared__ float Bs[2][32][36];   // [gemm-wave][k][n], pad 36 (16B rows)

    const int tid  = threadIdx.x;
    const int wave = tid >> 6;
    const int lane = tid & 63;
    const int bid  = blockIdx.x;

    if (wave < 2) {
        // ---------------- GEMM half (waves 0,1): 16x32 tile, K=1024 --------
        const int w  = bid * 2 + wave;        // 0..511
        const int m0 = (w & 15) << 4;         // 16 m-tiles
        const int n0 = (w >> 4) << 5;         // 32 n-tiles

        float (*A)[17] = As[wave];
        float (*B)[36] = Bs[wave];

        const int sm   = lane >> 2;           // A staging row 0..15
        const int skq  = (lane & 3) << 3;     // A staging k0: 0,8,16,24
        const int kl0  = lane >> 3;           // B staging k row base 0..7
        const int bc4  = (lane & 7) << 2;     // B staging col 0..28
        const int crow = lane >> 2;           // compute row 0..15
        const int ccol = (lane & 3) << 3;     // compute col 0,8,16,24

        float sv[5];
#pragma unroll
        for (int j = 0; j < 5; ++j) sv[j] = style_vectors[(m0 + sm) * 5 + j];

        f32x4 acc0 = {}, acc1 = {};

        for (int kc = 0; kc < 1024; kc += 32) {
            // ---- A tile [32k][16m] ----
            if (kc < DQ) {                    // style region: relu(sv@W1+b1)
                const int kg = kc + skq;
                f32x4 h0 = *(const f32x4*)&style_b1[kg];
                f32x4 h1 = *(const f32x4*)&style_b1[kg + 4];
#pragma unroll
                for (int j = 0; j < 5; ++j) {
                    h0 += sv[j] * *(const f32x4*)&style_w1[j * DQ + kg];
                    h1 += sv[j] * *(const f32x4*)&style_w1[j * DQ + kg + 4];
                }
#pragma unroll
                for (int r = 0; r < 4; ++r) {
                    A[skq + r][sm]     = fmaxf(h0[r], 0.0f);
                    A[skq + 4 + r][sm] = fmaxf(h1[r], 0.0f);
                }
            } else {                          // caption region
                const float* cap =
                    &page_captions[(m0 + sm) * TEXTC + (kc - DQ) + skq];
                f32x4 a0 = *(const f32x4*)cap;
                f32x4 a1 = *(const f32x4*)(cap + 4);
#pragma unroll
                for (int r = 0; r < 4; ++r) {
                    A[skq + r][sm]     = a0[r];
                    A[skq + 4 + r][sm] = a1[r];
                }
            }
            // ---- B tile [32k][32n] ----
#pragma unroll
            for (int h = 0; h < 4; ++h) {
                int kl   = kl0 + (h << 3);
                int krow = kc + kl;
                const float* Wrow = (krow < DQ) ? &style_w2[krow * D]
                                                : &text_w[(krow - DQ) * D];
                *(f32x4*)&B[kl][bc4] = *(const f32x4*)&Wrow[n0 + bc4];
            }
            __builtin_amdgcn_wave_barrier();   // stage -> compute
#pragma unroll
            for (int kk = 0; kk < 32; ++kk) {
                float a  = A[kk][crow];
                f32x4 b0 = *(const f32x4*)&B[kk][ccol];
                f32x4 b1 = *(const f32x4*)&B[kk][ccol + 4];
                acc0 += a * b0;
                acc1 += a * b1;
            }
            __builtin_amdgcn_wave_barrier();   // compute -> next stage
        }

        acc0 += *(const f32x4*)&style_b2[n0 + ccol]
              + *(const f32x4*)&text_b[n0 + ccol];
        acc1 += *(const f32x4*)&style_b2[n0 + ccol + 4]
              + *(const f32x4*)&text_b[n0 + ccol + 4];
        *(f32x4*)&comb[(m0 + crow) * D + n0 + ccol]     = acc0;
        *(f32x4*)&comb[(m0 + crow) * D + n0 + ccol + 4] = acc1;

        __threadfence();                       // drain + L2 writeback
        if (lane == 0)
            __hip_atomic_fetch_add(&g_done, 1, __ATOMIC_RELEASE,
                                   __HIP_MEMORY_SCOPE_AGENT);
    } else {
        // ---------------- writer half (waves 2..7) -------------------------
        const int wid  = bid * 6 + (wave - 2);          // 0..1535
        const int ROWS = (wid < NROWS - 21 * WRITE_WAVES) ? 22 : 21;
        int myet = 0, myei = 0;
        if (lane < ROWS) {
            const int grow = wid + WRITE_WAVES * lane;
            myet = types[grow];
            myei = indices[grow];
            out_mask[grow] = (myet == 0) ? 1.0f : 0.0f;
        }

        // phase 1: et != 1 rows (the GEMM shadow)
        for (int r = 0; r < ROWS; ++r) {
            const int et = __shfl(myet, r);
            if (et == 1) continue;
            const int ei = __shfl(myei, r);
            const int bs = wid + WRITE_WAVES * r;
            const int s  = bs & 127;
            const f32x4* te = (const f32x4*)&type_emb[et * D];
            const f32x4* pe = (const f32x4*)&pos_emb[ei * D];
            const f32x4* fe = (const f32x4*)&final_pos_emb[s * D];
            f32x4* dst = (f32x4*)out_emb + (size_t)bs * 256;
#pragma unroll
            for (int j = 0; j < 4; ++j) {
                int idx = lane + (j << 6);
                f32x4 v = te[idx] + pe[idx] + fe[idx];
                __builtin_nontemporal_store(v, &dst[idx]);
            }
        }

        // wait for GEMM completion (usually already done)
        while (__hip_atomic_load(&g_done, __ATOMIC_ACQUIRE,
                                 __HIP_MEMORY_SCOPE_AGENT) < GEMM_WAVES)
            __builtin_amdgcn_s_sleep(16);
        __threadfence();                       // invalidate stale L1/L2

        // phase 2: et == 1 rows (+ comb[b])
        const f32x4* te1 = (const f32x4*)&type_emb[1 * D];
        for (int r = 0; r < ROWS; ++r) {
            const int et = __shfl(myet, r);
            if (et != 1) continue;
            const int ei = __shfl(myei, r);
            const int bs = wid + WRITE_WAVES * r;
            const int b  = bs >> 7;
            const int s  = bs & 127;
            const f32x4* pe = (const f32x4*)&pos_emb[ei * D];
            const f32x4* fe = (const f32x4*)&final_pos_emb[s * D];
            const f32x4* cb = (const f32x4*)&comb[b * D];
            f32x4* dst = (f32x4*)out_emb + (size_t)bs * 256;
#pragma unroll
            for (int j = 0; j < 4; ++j) {
                int idx = lane + (j << 6);
                f32x4 v = te1[idx] + pe[idx] + fe[idx] + cb[idx];
                __builtin_nontemporal_store(v, &dst[idx]);
            }
        }

        // self-reset for the next graph replay: last writer wave zeroes flags
        if (lane == 0) {
            int n = __hip_atomic_fetch_add(&g_exit, 1, __ATOMIC_ACQ_REL,
                                           __HIP_MEMORY_SCOPE_AGENT);
            if (n == WRITE_WAVES - 1) {
                __hip_atomic_store(&g_done, 0, __ATOMIC_RELAXED,
                                   __HIP_MEMORY_SCOPE_AGENT);
                __hip_atomic_store(&g_exit, 0, __ATOMIC_RELAXED,
                                   __HIP_MEMORY_SCOPE_AGENT);
            }
        }
    }
}

// ---------------------------------------------------------------------------
extern "C" void kernel_launch(void* const* d_in, const int* in_sizes, int n_in,
                              void* d_out, int out_size, void* d_ws, size_t ws_size,
                              hipStream_t stream) {
    const int*   element_types   = (const int*)  d_in[0];
    const int*   element_indices = (const int*)  d_in[1];
    const float* style_vectors   = (const float*)d_in[2];
    const float* page_captions   = (const float*)d_in[3];
    const float* type_emb        = (const float*)d_in[4];
    const float* pos_emb         = (const float*)d_in[5];
    const float* style_w1        = (const float*)d_in[6];
    const float* style_b1        = (const float*)d_in[7];
    const float* style_w2        = (const float*)d_in[8];
    const float* style_b2        = (const float*)d_in[9];
    const float* text_w          = (const float*)d_in[10];
    const float* text_b          = (const float*)d_in[11];
    const float* final_pos_emb   = (const float*)d_in[12];

    float* comb = (float*)d_ws;                           // 256*1024 = 1 MB

    float* out_emb  = (float*)d_out;                      // 256*128*1024
    float* out_mask = (float*)d_out + BATCH * SEQ * D;    // 256*128

    fused_all<<<256, 512, 0, stream>>>(
        element_types, element_indices, type_emb, pos_emb, final_pos_emb,
        style_vectors, page_captions, style_w1, style_b1,
        style_w2, style_b2, text_w, text_b,
        comb, out_emb, out_mask);
}

// Round 4
// 193.852 us; speedup vs baseline: 4.7652x; 4.7652x over previous
//
#include <hip/hip_runtime.h>

#define D      1024
#define SEQ    128
#define BATCH  256
#define DQ     256
#define TEXTC  768

typedef float f32x4 __attribute__((ext_vector_type(4)));

// ---------------------------------------------------------------------------
// REVERT to round-2 structure (measured 192.0 us). Round-3's single-dispatch
// persistent-kernel grid sync (writer waves spin-gating on GEMM completion)
// collapsed to 924 us: GEMM global loads latency-exposed under the NT-store
// flood + acquire-poll invalidates. The kernel boundary IS the cheap sync.
//
// Kernel 1 — wave-specialized: GEMM hidden under the output write stream.
//   waves 0-1: one wave-private 16x64 (K=256) partial GEMM tile each
//              -> part[z][m][n]. 512 blocks x 2 = 1024 wave-tiles
//              = 16 m-tiles x 16 n-tiles x 4 z-chunks.
//              LDS tiles are wave-private => NO __syncthreads anywhere
//              (wave64 lockstep + compiler lgkmcnt = wave-synchronous).
//   waves 2-3: scatter rows [bid*64+(w-2)*32, +32): for et!=1 rows write
//              te+pe+fe (107 MB, 80% of output) + mask for ALL rows.
//              et==1 rows are left for kernel 2 (they need the full GEMM).
// Timeline per CU: GEMM waves done ~5-8us, write waves saturate HBM ~18us.
// ---------------------------------------------------------------------------
__global__ __launch_bounds__(256) void k1_gemm_scatter(
    const int* __restrict__ types,           // [256][128]
    const int* __restrict__ indices,         // [256][128]
    const float* __restrict__ type_emb,      // [5][1024]
    const float* __restrict__ pos_emb,       // [128][1024]
    const float* __restrict__ final_pos_emb, // [128][1024]
    const float* __restrict__ style_vectors, // [256][5]
    const float* __restrict__ page_captions, // [256][768]
    const float* __restrict__ style_w1,      // [5][256]
    const float* __restrict__ style_b1,      // [256]
    const float* __restrict__ style_w2,      // [256][1024]
    const float* __restrict__ style_b2,      // [1024]
    const float* __restrict__ text_w,        // [768][1024]
    const float* __restrict__ text_b,        // [1024]
    float* __restrict__ part,                // [4][256][1024]
    float* __restrict__ out_emb,             // [256][128][1024]
    float* __restrict__ out_mask)            // [256][128]
{
    __shared__ float As[2][32][20];   // [wave][k][m], pad 20 (16B-aligned rows)
    __shared__ float Bs[2][32][68];   // [wave][k][n], pad 68 (16B-aligned rows)

    const int tid  = threadIdx.x;
    const int wave = tid >> 6;
    const int lane = tid & 63;
    const int bid  = blockIdx.x;

    if (wave < 2) {
        // ------------------- GEMM half (waves 0,1) -------------------
        const int w   = bid * 2 + wave;       // 0..1023
        const int z   = w >> 8;               // K chunk [z*256, z*256+256)
        const int rem = w & 255;
        const int m0  = (rem & 15) << 4;      // 16-row tile
        const int n0  = (rem >> 4) << 6;      // 64-col tile

        float (*A)[20] = As[wave];
        float (*B)[68] = Bs[wave];

        const int sm  = lane >> 2;            // staging row 0..15
        const int sk  = (lane & 3) << 3;      // staging k0: 0,8,16,24
        const int tm4 = (lane >> 4) << 2;     // compute rows tm4..tm4+3
        const int tn4 = (lane & 15) << 2;     // compute cols tn4..tn4+3
        const int bkl = lane >> 4;            // B staging k row base

        float sv[5];
        if (z == 0) {
#pragma unroll
            for (int j = 0; j < 5; ++j) sv[j] = style_vectors[(m0 + sm) * 5 + j];
        }

        f32x4 acc[4] = {};                    // acc[r] = row tm4+r, 4 cols

        for (int kc = 0; kc < 256; kc += 32) {
            // ---- A tile [32k][16m]: relu(sv@W1+b1) (z=0) or captions ----
            if (z == 0) {
                const int kg = kc + sk;
                f32x4 h0 = *(const f32x4*)&style_b1[kg];
                f32x4 h1 = *(const f32x4*)&style_b1[kg + 4];
#pragma unroll
                for (int j = 0; j < 5; ++j) {
                    h0 += sv[j] * *(const f32x4*)&style_w1[j * DQ + kg];
                    h1 += sv[j] * *(const f32x4*)&style_w1[j * DQ + kg + 4];
                }
#pragma unroll
                for (int r = 0; r < 4; ++r) {
                    A[sk + r][sm]     = fmaxf(h0[r], 0.0f);
                    A[sk + 4 + r][sm] = fmaxf(h1[r], 0.0f);
                }
            } else {
                const float* cap =
                    &page_captions[(m0 + sm) * TEXTC + (z - 1) * 256 + kc + sk];
                f32x4 a0 = *(const f32x4*)cap;
                f32x4 a1 = *(const f32x4*)(cap + 4);
#pragma unroll
                for (int r = 0; r < 4; ++r) {
                    A[sk + r][sm]     = a0[r];
                    A[sk + 4 + r][sm] = a1[r];
                }
            }
            // ---- B tile [32k][64n] ----
#pragma unroll
            for (int h = 0; h < 8; ++h) {
                int kl   = bkl + (h << 2);
                int krow = (z << 8) + kc + kl;
                const float* Wrow = (z == 0) ? &style_w2[krow * D]
                                             : &text_w[(krow - DQ) * D];
                *(f32x4*)&B[kl][tn4] = *(const f32x4*)&Wrow[n0 + tn4];
            }
            __builtin_amdgcn_wave_barrier();   // pin stage->compute order
            // ---- 16 FMA per kk, wave-private, no block barrier ----
#pragma unroll
            for (int kk = 0; kk < 32; ++kk) {
                f32x4 a4 = *(const f32x4*)&A[kk][tm4];
                f32x4 b4 = *(const f32x4*)&B[kk][tn4];
#pragma unroll
                for (int r = 0; r < 4; ++r)
                    acc[r] += a4[r] * b4;
            }
            __builtin_amdgcn_wave_barrier();   // pin compute->next-stage order
        }

        f32x4 bias = {};
        if (z == 0)
            bias = *(const f32x4*)&style_b2[n0 + tn4]
                 + *(const f32x4*)&text_b[n0 + tn4];
#pragma unroll
        for (int r = 0; r < 4; ++r) {
            int m = m0 + tm4 + r;
            f32x4 v = acc[r];
            if (z == 0) v += bias;
            *(f32x4*)&part[((size_t)z * BATCH + m) * D + n0 + tn4] = v;
        }
    } else {
        // ------------------- scatter half (waves 2,3) -------------------
        const int r0 = bid * 64 + ((wave - 2) << 5);   // 32 rows per wave
        const int lr = lane & 31;
        const int myet = types[r0 + lr];
        const int myei = indices[r0 + lr];
        if (lane < 32)
            out_mask[r0 + lane] = (myet == 0) ? 1.0f : 0.0f;

#pragma unroll 4
        for (int r = 0; r < 32; ++r) {
            const int et = __shfl(myet, r);    // wave-uniform broadcast
            const int ei = __shfl(myei, r);
            if (et == 1) continue;             // kernel 2's job
            const int bs = r0 + r;
            const int s  = bs & 127;
            const f32x4* te = (const f32x4*)&type_emb[et * D];
            const f32x4* pe = (const f32x4*)&pos_emb[ei * D];
            const f32x4* fe = (const f32x4*)&final_pos_emb[s * D];
            f32x4* dst = (f32x4*)out_emb + (size_t)bs * 256;
#pragma unroll
            for (int j = 0; j < 4; ++j) {
                int idx = lane + (j << 6);
                f32x4 v = te[idx] + pe[idx] + fe[idx];
                __builtin_nontemporal_store(v, &dst[idx]);
            }
        }
    }
}

// ---------------------------------------------------------------------------
// Kernel 2 — et==1 rows only. comb = sum_z part[z][b] staged ONCE per block
// in LDS (part reads: 105 MB -> 8 MB), then stream the remaining ~27 MB.
// Grid 512 = (b, s-half); 4 waves x 16 rows, wave-per-row writes.
// ---------------------------------------------------------------------------
__global__ __launch_bounds__(256) void k2_comb_scatter(
    const int* __restrict__ types,
    const int* __restrict__ indices,
    const float* __restrict__ type_emb,
    const float* __restrict__ pos_emb,
    const float* __restrict__ final_pos_emb,
    const float* __restrict__ part,          // [4][256][1024]
    float* __restrict__ out_emb)
{
    __shared__ f32x4 comb[256];              // one 1024-float row

    const int tid = threadIdx.x;
    const int bid = blockIdx.x;
    const int b   = bid >> 1;
    const int sh  = (bid & 1) << 6;

    {
        const int Q = BATCH * D / 4;         // f32x4 per z-plane
        const f32x4* p = (const f32x4*)part + b * 256 + tid;
        comb[tid] = p[0] + p[Q] + p[2 * Q] + p[3 * Q];
    }
    __syncthreads();

    const int wave = tid >> 6;
    const int lane = tid & 63;
    const int s0   = sh + (wave << 4);       // 16 rows per wave
    const int bs0  = (b << 7) + s0;
    const int myet = types[bs0 + (lane & 15)];
    const int myei = indices[bs0 + (lane & 15)];

#pragma unroll 4
    for (int r = 0; r < 16; ++r) {
        const int et = __shfl(myet, r);
        const int ei = __shfl(myei, r);
        if (et != 1) continue;
        const int bs = bs0 + r;
        const int s  = s0 + r;
        const f32x4* te = (const f32x4*)&type_emb[et * D];   // et==1
        const f32x4* pe = (const f32x4*)&pos_emb[ei * D];
        const f32x4* fe = (const f32x4*)&final_pos_emb[s * D];
        f32x4* dst = (f32x4*)out_emb + (size_t)bs * 256;
#pragma unroll
        for (int j = 0; j < 4; ++j) {
            int idx = lane + (j << 6);
            f32x4 v = te[idx] + pe[idx] + fe[idx] + comb[idx];
            __builtin_nontemporal_store(v, &dst[idx]);
        }
    }
}

// ---------------------------------------------------------------------------
extern "C" void kernel_launch(void* const* d_in, const int* in_sizes, int n_in,
                              void* d_out, int out_size, void* d_ws, size_t ws_size,
                              hipStream_t stream) {
    const int*   element_types   = (const int*)  d_in[0];
    const int*   element_indices = (const int*)  d_in[1];
    const float* style_vectors   = (const float*)d_in[2];
    const float* page_captions   = (const float*)d_in[3];
    const float* type_emb        = (const float*)d_in[4];
    const float* pos_emb         = (const float*)d_in[5];
    const float* style_w1        = (const float*)d_in[6];
    const float* style_b1        = (const float*)d_in[7];
    const float* style_w2        = (const float*)d_in[8];
    const float* style_b2        = (const float*)d_in[9];
    const float* text_w          = (const float*)d_in[10];
    const float* text_b          = (const float*)d_in[11];
    const float* final_pos_emb   = (const float*)d_in[12];

    float* part = (float*)d_ws;                           // 4*256*1024 = 4 MB

    float* out_emb  = (float*)d_out;                      // 256*128*1024
    float* out_mask = (float*)d_out + BATCH * SEQ * D;    // 256*128

    // 1) GEMM (hidden) + 80% of output stream + mask
    k1_gemm_scatter<<<512, 256, 0, stream>>>(
        element_types, element_indices, type_emb, pos_emb, final_pos_emb,
        style_vectors, page_captions, style_w1, style_b1,
        style_w2, style_b2, text_w, text_b,
        part, out_emb, out_mask);

    // 2) et==1 rows: comb staged in LDS, remaining ~20% of output stream
    k2_comb_scatter<<<512, 256, 0, stream>>>(
        element_types, element_indices, type_emb, pos_emb, final_pos_emb,
        part, out_emb);
}